// Round 2
// baseline (607.627 us; speedup 1.0000x reference)
//
#include <hip/hip_runtime.h>
#include <math.h>

#define B 2048
#define C 1024

// ---------------------------------------------------------------------------
// Kernel 1: row softmax of y/2 for both inputs. grid 2*B blocks, 256 thr.
// Each thread owns one float4 of the 1024-wide row.
// ---------------------------------------------------------------------------
__global__ __launch_bounds__(256) void softmax_k(const float* __restrict__ ys,
                                                 const float* __restrict__ yt,
                                                 float* __restrict__ ps,
                                                 float* __restrict__ pt) {
    int b = blockIdx.x;
    const float* in;
    float* out;
    if (b < B) { in = ys + (size_t)b * C;        out = ps + (size_t)b * C; }
    else       { in = yt + (size_t)(b - B) * C;  out = pt + (size_t)(b - B) * C; }
    int tid = threadIdx.x;
    int lane = tid & 63, wave = tid >> 6;

    float4 v = reinterpret_cast<const float4*>(in)[tid];
    v.x *= 0.5f; v.y *= 0.5f; v.z *= 0.5f; v.w *= 0.5f;

    float mx = fmaxf(fmaxf(v.x, v.y), fmaxf(v.z, v.w));
    #pragma unroll
    for (int m = 32; m >= 1; m >>= 1) mx = fmaxf(mx, __shfl_xor(mx, m, 64));
    __shared__ float redm[4];
    if (lane == 0) redm[wave] = mx;
    __syncthreads();
    mx = fmaxf(fmaxf(redm[0], redm[1]), fmaxf(redm[2], redm[3]));

    float4 e;
    e.x = expf(v.x - mx); e.y = expf(v.y - mx);
    e.z = expf(v.z - mx); e.w = expf(v.w - mx);
    float s = e.x + e.y + e.z + e.w;
    #pragma unroll
    for (int m = 32; m >= 1; m >>= 1) s += __shfl_xor(s, m, 64);
    __shared__ float reds[4];
    if (lane == 0) reds[wave] = s;
    __syncthreads();
    s = reds[0] + reds[1] + reds[2] + reds[3];

    float inv = 1.0f / s;
    e.x *= inv; e.y *= inv; e.z *= inv; e.w *= inv;
    reinterpret_cast<float4*>(out)[tid] = e;
}

// ---------------------------------------------------------------------------
// Kernel 2: K[i][j] = exp(-10 * W[i][j]),  W = 2 - 2*sum_c min(ps[i,c], pt[j,c])
// 64x64 tile per block, BK=16 k-chunk, k-major LDS with pad 68 (16B-aligned
// rows, <=2-way bank aliasing on b128 reads). 4x4 outputs per thread.
// ---------------------------------------------------------------------------
__global__ __launch_bounds__(256) void cdist_k(const float* __restrict__ ps,
                                               const float* __restrict__ pt,
                                               float* __restrict__ Km) {
    __shared__ __align__(16) float As[16][68];
    __shared__ __align__(16) float Bs[16][68];
    int tid = threadIdx.x;
    int tx = tid & 15, ty = tid >> 4;
    int r0 = blockIdx.y * 64, c0 = blockIdx.x * 64;

    float acc[4][4];
    #pragma unroll
    for (int i = 0; i < 4; ++i)
        #pragma unroll
        for (int j = 0; j < 4; ++j) acc[i][j] = 0.f;

    int lr = tid >> 2;          // row within tile 0..63
    int lk = (tid & 3) * 4;     // k offset 0,4,8,12
    const float4* pa = reinterpret_cast<const float4*>(ps + (size_t)(r0 + lr) * C);
    const float4* pb = reinterpret_cast<const float4*>(pt + (size_t)(c0 + lr) * C);

    for (int kk = 0; kk < C; kk += 16) {
        float4 av = pa[(kk + lk) >> 2];
        float4 bv = pb[(kk + lk) >> 2];
        As[lk + 0][lr] = av.x; As[lk + 1][lr] = av.y;
        As[lk + 2][lr] = av.z; As[lk + 3][lr] = av.w;
        Bs[lk + 0][lr] = bv.x; Bs[lk + 1][lr] = bv.y;
        Bs[lk + 2][lr] = bv.z; Bs[lk + 3][lr] = bv.w;
        __syncthreads();
        #pragma unroll
        for (int k = 0; k < 16; ++k) {
            float4 a4 = *reinterpret_cast<const float4*>(&As[k][ty * 4]);
            float4 b4 = *reinterpret_cast<const float4*>(&Bs[k][tx * 4]);
            float ar[4] = {a4.x, a4.y, a4.z, a4.w};
            float br[4] = {b4.x, b4.y, b4.z, b4.w};
            #pragma unroll
            for (int i = 0; i < 4; ++i)
                #pragma unroll
                for (int j = 0; j < 4; ++j)
                    acc[i][j] += fminf(ar[i], br[j]);
        }
        __syncthreads();
    }

    #pragma unroll
    for (int i = 0; i < 4; ++i) {
        int row = r0 + ty * 4 + i;
        float4 kv;
        kv.x = expf(20.f * acc[i][0] - 20.f);   // exp(-10*(2-2S)) = exp(20S-20)
        kv.y = expf(20.f * acc[i][1] - 20.f);
        kv.z = expf(20.f * acc[i][2] - 20.f);
        kv.w = expf(20.f * acc[i][3] - 20.f);
        *reinterpret_cast<float4*>(&Km[(size_t)row * B + c0 + tx * 4]) = kv;
    }
}

// ---------------------------------------------------------------------------
// Kernel 3: bsum[0][j] = 1.0  (b starts as ones, stored as s with b = 1/s)
// ---------------------------------------------------------------------------
__global__ void init_b0(float* __restrict__ b0) {
    int i = blockIdx.x * blockDim.x + threadIdx.x;
    if (i < B) b0[i] = 1.0f;
}

// ---------------------------------------------------------------------------
// Kernel 4: a_i = 1 / sum_j K[i][j] * (1/sprev[j]).  256 blocks x 8 rows.
// ---------------------------------------------------------------------------
__global__ __launch_bounds__(256) void mv_rows(const float* __restrict__ Km,
                                               const float* __restrict__ sprev,
                                               float* __restrict__ a) {
    __shared__ float binv[B];
    int tid = threadIdx.x;
    for (int j = tid; j < B; j += 256) binv[j] = 1.0f / sprev[j];
    __syncthreads();
    int lane = tid & 63, wave = tid >> 6;
    const float4* bi = reinterpret_cast<const float4*>(binv);
    #pragma unroll
    for (int rr = 0; rr < 2; ++rr) {
        int row = blockIdx.x * 8 + wave * 2 + rr;
        const float4* Kr = reinterpret_cast<const float4*>(Km + (size_t)row * B);
        float acc = 0.f;
        #pragma unroll
        for (int ch = 0; ch < 8; ++ch) {
            float4 kv = Kr[ch * 64 + lane];
            float4 bv = bi[ch * 64 + lane];
            acc += kv.x * bv.x + kv.y * bv.y + kv.z * bv.z + kv.w * bv.w;
        }
        #pragma unroll
        for (int m = 32; m >= 1; m >>= 1) acc += __shfl_xor(acc, m, 64);
        if (lane == 0) a[row] = 1.0f / acc;
    }
}

// ---------------------------------------------------------------------------
// Kernel 5: sout[j] += sum_{i in slab} K[i][j] * a[i].  grid (4,64): 512 cols
// per x-block (float2/thread), 32-row slab per y-block. sout pre-zeroed.
// ---------------------------------------------------------------------------
__global__ __launch_bounds__(256) void mv_cols(const float* __restrict__ Km,
                                               const float* __restrict__ a,
                                               float* __restrict__ sout) {
    __shared__ float av[32];
    int tid = threadIdx.x;
    int c = blockIdx.x * 512 + tid * 2;
    int r0 = blockIdx.y * 32;
    if (tid < 32) av[tid] = a[r0 + tid];
    __syncthreads();
    float ax = 0.f, ay = 0.f;
    #pragma unroll 4
    for (int i = 0; i < 32; ++i) {
        float2 kv = *reinterpret_cast<const float2*>(&Km[(size_t)(r0 + i) * B + c]);
        float w = av[i];
        ax += w * kv.x;
        ay += w * kv.y;
    }
    atomicAdd(&sout[c], ax);
    atomicAdd(&sout[c + 1], ay);
}

// ---------------------------------------------------------------------------
// Kernel 6: per-block partial of loss = sum_ij a_i K_ij (-0.1 ln K_ij) / s20_j
// Same row-slab structure as mv_rows.
// ---------------------------------------------------------------------------
__global__ __launch_bounds__(256) void loss_rows(const float* __restrict__ Km,
                                                 const float* __restrict__ a,
                                                 const float* __restrict__ s20,
                                                 float* __restrict__ lpart) {
    __shared__ float binv[B];
    int tid = threadIdx.x;
    for (int j = tid; j < B; j += 256) binv[j] = 1.0f / s20[j];
    __syncthreads();
    int lane = tid & 63, wave = tid >> 6;
    const float4* bi = reinterpret_cast<const float4*>(binv);
    float wave_part = 0.f;
    #pragma unroll
    for (int rr = 0; rr < 2; ++rr) {
        int row = blockIdx.x * 8 + wave * 2 + rr;
        const float4* Kr = reinterpret_cast<const float4*>(Km + (size_t)row * B);
        float acc = 0.f;
        for (int ch = 0; ch < 8; ++ch) {
            float4 kv = Kr[ch * 64 + lane];
            float4 bv = bi[ch * 64 + lane];
            acc += kv.x * bv.x * __logf(kv.x);
            acc += kv.y * bv.y * __logf(kv.y);
            acc += kv.z * bv.z * __logf(kv.z);
            acc += kv.w * bv.w * __logf(kv.w);
        }
        #pragma unroll
        for (int m = 32; m >= 1; m >>= 1) acc += __shfl_xor(acc, m, 64);
        if (lane == 0) wave_part += -0.1f * a[row] * acc;
    }
    __shared__ float red[4];
    if (lane == 0) red[wave] = wave_part;
    __syncthreads();
    if (tid == 0) lpart[blockIdx.x] = red[0] + red[1] + red[2] + red[3];
}

// ---------------------------------------------------------------------------
// Kernel 7: final reduce of 256 partials -> d_out[0]
// ---------------------------------------------------------------------------
__global__ __launch_bounds__(256) void loss_final(const float* __restrict__ lpart,
                                                  float* __restrict__ out) {
    int tid = threadIdx.x;
    int lane = tid & 63, wave = tid >> 6;
    float v = lpart[tid];
    #pragma unroll
    for (int m = 32; m >= 1; m >>= 1) v += __shfl_xor(v, m, 64);
    __shared__ float red[4];
    if (lane == 0) red[wave] = v;
    __syncthreads();
    if (tid == 0) out[0] = 0.001f * (red[0] + red[1] + red[2] + red[3]);
}

// ---------------------------------------------------------------------------
extern "C" void kernel_launch(void* const* d_in, const int* in_sizes, int n_in,
                              void* d_out, int out_size, void* d_ws, size_t ws_size,
                              hipStream_t stream) {
    const float* ys = (const float*)d_in[0];
    const float* yt = (const float*)d_in[1];
    float* out = (float*)d_out;

    float* ws    = (float*)d_ws;
    float* ps    = ws;                       // B*C
    float* pt    = ps + (size_t)B * C;       // B*C
    float* Km    = pt + (size_t)B * C;       // B*B
    float* a     = Km + (size_t)B * B;       // B
    float* bsum  = a + B;                    // 21*B (s-vectors, b = 1/s)
    float* lpart = bsum + (size_t)21 * B;    // 256

    // zero the 20 accumulation targets bsum[1..20]
    (void)hipMemsetAsync(bsum + B, 0, (size_t)20 * B * sizeof(float), stream);

    softmax_k<<<2 * B, 256, 0, stream>>>(ys, yt, ps, pt);
    init_b0<<<8, 256, 0, stream>>>(bsum);
    cdist_k<<<dim3(32, 32), 256, 0, stream>>>(ps, pt, Km);

    for (int t = 1; t <= 20; ++t) {
        mv_rows<<<256, 256, 0, stream>>>(Km, bsum + (size_t)(t - 1) * B, a);
        mv_cols<<<dim3(4, 64), 256, 0, stream>>>(Km, a, bsum + (size_t)t * B);
    }

    loss_rows<<<256, 256, 0, stream>>>(Km, a, bsum + (size_t)20 * B, lpart);
    loss_final<<<1, 256, 0, stream>>>(lpart, out);
}